// Round 19
// baseline (90.601 us; speedup 1.0000x reference)
//
#include <hip/hip_runtime.h>
#include <hip/hip_cooperative_groups.h>
#include <math.h>

namespace cg = cooperative_groups;

static constexpr int B_ = 32;
static constexpr int RES_ = 50;
static constexpr int CAP = 2048;            // per (hq,b,part) bucket capacity
#define NF (1.0f/(2.0f*0.05f*0.05f + 1e-8f))
#define QSCALE 2048.0f                      // u16 bin quantization
#define QINV   (1.0f / 2048.0f)
#define EX(x)  __builtin_amdgcn_exp2f(x)    // native v_exp_f32 (2^x)
#define SQ(x)  ((x)*(x))

// pack = ix<<24 | iy<<16 | v  (NN bins, quantized weight)
__device__ __forceinline__ unsigned packpt(float bx, float dy) {
    int ix = (int)(fminf(fmaxf(bx * 255.0f + 0.5f, 0.0f), 255.0f));
    int iy = (int)(fminf(fmaxf(dy * 255.0f + 0.5f, 0.0f), 255.0f));
    float pers = fminf(fabsf(dy - bx), 10.0f);
    unsigned v = (unsigned)(fminf(pers * pers * QSCALE, 65535.0f) + 0.5f);
    return ((unsigned)ix << 24) | ((unsigned)iy << 16) | v;
}

// ---------------------------------------------------------------------------
// MEGA kernel, cooperative: 256 blocks x 1024 thr x 76 KB LDS = 1 block/CU
// (all co-resident -> grid.sync() legal). id%8 == b%8 in every phase keeps
// each batch's data on one XCD's L2 across phases.
//   Phase A (bucket): block (hq:8, b:32) packs 8192 points once and scatters
//     them into pkb[(hq*32+b)][part:8][slot:CAP] via LDS ds_add_rtn counters
//     (counters alias the tile region; buckets padded to x4 with v=0 no-ops).
//   Phase B (fused): block (part:8, b:32) owns region (xh=part&1, yo=part>>1);
//     scans its 8 bucket segments (all lanes active, 1 packed ds_add_u32/pt)
//     into a 16 KB packed-u16 tile; stage1 cx-contraction vs Gaussian-x slot
//     table (slot ig*8+k -> row i=ig*7+k, k<7, i<50); stage2 cy-contraction
//     with inline-exp Gaussian-y -> partial[part*32+b][50][50] (L2-resident).
//   Phase C (reduce): all 256 blocks; out[b][f] = sum_part partial (L2-hot).
// ---------------------------------------------------------------------------
__global__ void __launch_bounds__(1024, 1)
k_mega(const float4* __restrict__ pts, unsigned* __restrict__ pkb,
       unsigned* __restrict__ cnt4, float* __restrict__ partial,
       float* __restrict__ out) {
    extern __shared__ unsigned lds[];
    unsigned* tile = lds;                        // 4096 u32 (16 KB)
    float* gx   = (float*)(lds + 4096);          // 8192 f32 (32 KB)
    float* tmpP = (float*)(lds + 4096 + 8192);   // 7168 f32 (28 KB)

    int id  = blockIdx.x;
    int b   = id & 31;
    int tid = threadIdx.x;
    const float S2 = sqrtf(NF * 1.44269504f);    // const-folded

    // ===== Phase A: pack + bucket =====
    {
        unsigned* lcnt = lds;                    // aliases tile (rezeroed in B)
        if (tid < 8) lcnt[tid] = 0u;
        __syncthreads();
        int hq = id >> 5;
        const float4* src = pts + ((size_t)b << 15) + ((size_t)hq << 12);
        unsigned* mybase = pkb + ((size_t)id << 14);     // 8*CAP u32
        for (int t = tid; t < 4096; t += 1024) {
            float4 q = src[t];
#pragma unroll
            for (int h = 0; h < 2; h++) {
                float bx = h ? q.z : q.x;
                float dy = h ? q.w : q.y;
                unsigned u = packpt(bx, dy);
                int part = ((int)((u >> 22) & 3u) << 1) | (int)(u >> 31);
                unsigned slot = atomicAdd(&lcnt[part], 1u);
                if (slot < (unsigned)CAP) mybase[(part << 11) + slot] = u;
            }
        }
        __syncthreads();
        if (tid < 8) {
            unsigned base = lcnt[tid]; if (base > (unsigned)CAP) base = CAP;
            unsigned padded = (base + 3u) & ~3u; if (padded > (unsigned)CAP) padded = CAP;
            for (unsigned k = base; k < padded; k++)
                mybase[((unsigned)tid << 11) + k] = 0u;
            cnt4[(id << 3) + tid] = padded >> 2;
        }
    }

    cg::this_grid().sync();

    // ===== Phase B: fused splat + 2-stage contraction =====
    {
        int part = id >> 5;
        int xh = part & 1, yo = part >> 1;

        for (int t = tid; t < 4096; t += 1024) tile[t] = 0u;
        for (int t = tid; t < 8192; t += 1024) {
            int cxL = t >> 6, s = t & 63;
            int ig = s >> 3, k = s & 7;
            int i = ig * 7 + k;
            float v = 0.0f;
            if (k < 7 && i < RES_) {
                float d = ((float)i * (1.0f / 49.0f)
                         - (float)((xh << 7) + cxL) * (1.0f / 255.0f)) * S2;
                v = EX(-SQ(d));
            }
            gx[t] = v;
        }
        __syncthreads();

        int xlo = xh << 7, ylo = yo << 6;
        for (int hq = 0; hq < 8; hq++) {
            int blk = (hq << 5) + b;
            int n4 = (int)cnt4[(blk << 3) + part];
            const uint4* src = (const uint4*)(pkb + ((size_t)blk << 14) + (part << 11));
            for (int t = tid; t < n4; t += 1024) {
                uint4 q = src[t];
#pragma unroll
                for (int e = 0; e < 4; e++) {
                    unsigned u = e == 0 ? q.x : (e == 1 ? q.y : (e == 2 ? q.z : q.w));
                    int lx = (int)(u >> 24) - xlo;
                    int ly = (int)((u >> 16) & 255u) - ylo;
                    if (((unsigned)lx < 128u) & ((unsigned)ly < 64u))
                        atomicAdd(tile + (lx << 5) + (ly >> 1),
                                  (u & 0xffffu) << ((ly & 1) << 4));
                }
            }
        }
        __syncthreads();

        // stage1: tmp[i][cyL] = sum_cx gx[cx][i] * tile[cx][cyL]
        {
            int cyL = tid & 63;
            int ig  = (tid >> 6) & 7;       // wave-uniform
            int cxh = tid >> 9;             // wave-uniform
            float acc[7];
#pragma unroll
            for (int k = 0; k < 7; k++) acc[k] = 0.0f;
#pragma unroll 4
            for (int c = 0; c < 64; c++) {
                int cx = (cxh << 6) + c;
                unsigned wrd = tile[(cx << 5) + (cyL >> 1)];
                float hv = (float)((wrd >> ((cyL & 1) << 4)) & 0xffffu) * QINV;
                const float* g = gx + (cx << 6) + (ig << 3);
                float4 g0 = *(const float4*)(g);
                float4 g1 = *(const float4*)(g + 4);
                acc[0] += g0.x * hv;  acc[1] += g0.y * hv;
                acc[2] += g0.z * hv;  acc[3] += g0.w * hv;
                acc[4] += g1.x * hv;  acc[5] += g1.y * hv;
                acc[6] += g1.z * hv;             // slot 7 = zero pad
            }
            float* tp = tmpP + (size_t)cxh * 3584 + (ig * 7) * 64 + cyL;
#pragma unroll
            for (int k = 0; k < 7; k++) tp[k * 64] = acc[k];
        }
        __syncthreads();
        for (int t = tid; t < 3584; t += 1024) tmpP[t] += tmpP[t + 3584];
        __syncthreads();

        // stage2: out[i][j] = sum_cy tmp[i][cy] * gy[ylo+cy][j]
        {
            int j  = tid & 63;
            int iq = tid >> 6;              // 0..15, use 0..13
            if (iq < 14) {
                int jc = j < RES_ ? j : RES_ - 1;
                float xjS = (float)jc * (1.0f / 49.0f) * S2;
                float a0 = 0.f, a1 = 0.f, a2 = 0.f, a3 = 0.f;
                const float* tq = tmpP + (iq * 4) * 64;
#pragma unroll 4
                for (int c = 0; c < 64; c++) {
                    float d = xjS - (float)(ylo + c) * (1.0f / 255.0f) * S2;
                    float g = EX(-SQ(d));
                    a0 += tq[c] * g;
                    a1 += tq[64 + c] * g;
                    a2 += tq[128 + c] * g;
                    a3 += tq[192 + c] * g;
                }
                if (j < RES_) {
                    float* dst = partial + (size_t)id * 2500;
                    int i0 = iq * 4;
                    if (i0 + 0 < RES_) dst[(i0 + 0) * RES_ + j] = a0;
                    if (i0 + 1 < RES_) dst[(i0 + 1) * RES_ + j] = a1;
                    if (i0 + 2 < RES_) dst[(i0 + 2) * RES_ + j] = a2;
                    if (i0 + 3 < RES_) dst[(i0 + 3) * RES_ + j] = a3;
                }
            }
        }
    }

    cg::this_grid().sync();

    // ===== Phase C: reduce 8 partials (L2-hot) =====
    {
        int oct = id >> 5;
        int lo = (oct * 2500) >> 3, hi = ((oct + 1) * 2500) >> 3;
        const float* p = partial + (size_t)b * 2500;
        for (int f = lo + tid; f < hi; f += 1024) {
            float s = 0.0f;
#pragma unroll
            for (int k = 0; k < 8; k++) s += p[(size_t)k * B_ * 2500 + f];
            out[(size_t)b * 2500 + f] = s;
        }
    }
}

// ---------------------------------------------------------------------------
extern "C" void kernel_launch(void* const* d_in, const int* in_sizes, int n_in,
                              void* d_out, int out_size, void* d_ws, size_t ws_size,
                              hipStream_t stream) {
    const float4* pts = (const float4*)d_in[0];
    unsigned* pkb  = (unsigned*)d_ws;                      // 256*16384 u32 = 16.8 MB
    unsigned* cnt4 = pkb + (size_t)256 * 16384;            // 2048 u32
    float* partial = (float*)(cnt4 + 2048);                // 256*2500 f32 = 2.56 MB
    float* out = (float*)d_out;

    hipFuncSetAttribute((const void*)k_mega,
                        hipFuncAttributeMaxDynamicSharedMemorySize, 77824);

    void* args[] = { (void*)&pts, (void*)&pkb, (void*)&cnt4,
                     (void*)&partial, (void*)&out };
    hipLaunchCooperativeKernel((const void*)k_mega, dim3(256), dim3(1024),
                               args, 77824, stream);
}

// Round 20
// 89.718 us; speedup vs baseline: 1.0098x; 1.0098x over previous
//
#include <hip/hip_runtime.h>
#include <math.h>

static constexpr int B_ = 32;
static constexpr int RES_ = 50;
static constexpr int CAP = 1024;            // per (hq,b,part) bucket capacity
#define NF (1.0f/(2.0f*0.05f*0.05f + 1e-8f))
#define QSCALE 2048.0f                      // u16 bin quantization
#define QINV   (1.0f / 2048.0f)
#define EX(x)  __builtin_amdgcn_exp2f(x)    // native v_exp_f32 (2^x)
#define SQ(x)  ((x)*(x))

// pack = ix<<24 | iy<<16 | v  (NN bins, quantized weight)
__device__ __forceinline__ unsigned packpt(float bx, float dy) {
    int ix = (int)(fminf(fmaxf(bx * 255.0f + 0.5f, 0.0f), 255.0f));
    int iy = (int)(fminf(fmaxf(dy * 255.0f + 0.5f, 0.0f), 255.0f));
    float pers = fminf(fabsf(dy - bx), 10.0f);
    unsigned v = (unsigned)(fminf(pers * pers * QSCALE, 65535.0f) + 0.5f);
    return ((unsigned)ix << 24) | ((unsigned)iy << 16) | v;
}

// ---------------------------------------------------------------------------
// K0: pack each point once and bucket by 64x64 region part = (iy>>6)*4+(ix>>6)
//     (16 parts). Grid 256 = (hq:8, b:32), id%32==b. LDS ds_add_rtn counters;
//     buckets padded to x4 with u=0 no-ops. Also zeroes done[] (block 0) so
//     the fused kernel's completion counters are reset every call (replay-safe).
//     pkb[(hq*32+b)][part:16][slot:CAP] u32; cnt4 = padded count / 4.
// ---------------------------------------------------------------------------
__global__ void __launch_bounds__(1024) k_bucket(const float4* __restrict__ pts,
                                                 unsigned* __restrict__ pkb,
                                                 unsigned* __restrict__ cnt4,
                                                 unsigned* __restrict__ done) {
    __shared__ unsigned lcnt[16];
    int id = blockIdx.x;
    int b = id & 31, hq = id >> 5;
    int tid = threadIdx.x;
    if (tid < 16) lcnt[tid] = 0u;
    if (id == 0 && tid < 32) done[tid] = 0u;
    __syncthreads();

    const float4* src = pts + ((size_t)b << 15) + ((size_t)hq << 12);  // 4096 f4
    unsigned* mybase = pkb + ((size_t)id << 14);    // 16 * CAP u32
    for (int t = tid; t < 4096; t += 1024) {
        float4 q = src[t];
#pragma unroll
        for (int h = 0; h < 2; h++) {
            float bx = h ? q.z : q.x;
            float dy = h ? q.w : q.y;
            unsigned u = packpt(bx, dy);
            int part = (int)(((u >> 22) & 3u) << 2) | (int)(u >> 30);
            unsigned slot = atomicAdd(&lcnt[part], 1u);
            if (slot < (unsigned)CAP) mybase[(part << 10) + slot] = u;
        }
    }
    __syncthreads();
    if (tid < 16) {
        unsigned base = lcnt[tid]; if (base > (unsigned)CAP) base = CAP;
        unsigned padded = (base + 3u) & ~3u; if (padded > (unsigned)CAP) padded = CAP;
        for (unsigned k = base; k < padded; k++)
            mybase[((unsigned)tid << 10) + k] = 0u;
        cnt4[(id << 4) + tid] = padded >> 2;
    }
}

// ---------------------------------------------------------------------------
// K1: FUSED splat + 2-stage contraction + last-block reduce.
//     Grid 512 = (part:16, b:32), id%8==b%8 (all 16 region-blocks of batch b
//     on one XCD: bucket reads L2-hot, partials L2-hot, done-counter valid).
//     2 blocks/CU (52 KB LDS, launch_bounds(1024,8)). Flattened bucket scan
//     (~1024 uint4 over 8 segments, prefix-select) -> 1 packed ds_add_u32/pt
//     into an 8 KB 64x64 packed-u16 tile. Stage1: cx-contraction vs 16 KB
//     Gaussian-x slot table (slot ig*8+k -> row i=ig*7+k, k<7, i<50), 1024thr
//     = cyL:64 x ig:8 x cxh:2 (32 cx each). Stage2: cy-contraction, inline
//     Gaussian-y -> partial[id][50][50]. Last arriving block of batch b
//     (device atomic done[b]) sums the 16 partials in fixed order -> out.
// ---------------------------------------------------------------------------
__global__ void __launch_bounds__(1024, 8)
k_fused(const unsigned* __restrict__ pkb, const unsigned* __restrict__ cnt4,
        float* __restrict__ partial, unsigned* __restrict__ done,
        float* __restrict__ out) {
    extern __shared__ unsigned lds[];
    unsigned* tile = lds;                        // 2048 u32 ( 8 KB)
    float* gx   = (float*)(lds + 2048);          // 4096 f32 (16 KB)
    float* tmpP = (float*)(lds + 2048 + 4096);   // 7168 f32 (28 KB)
    __shared__ unsigned amLast;

    int id = blockIdx.x;
    int b    = id & 31;
    int part = id >> 5;                     // 0..15
    int px = part & 3, py = part >> 2;
    int xlo = px << 6, ylo = py << 6;
    int tid = threadIdx.x;
    const float S2 = sqrtf(NF * 1.44269504f);   // const-folded

    // --- init: zero tile, build Gaussian-x slot table for this px ---
    for (int t = tid; t < 2048; t += 1024) tile[t] = 0u;
    for (int t = tid; t < 4096; t += 1024) {
        int cxL = t >> 6, s = t & 63;
        int ig = s >> 3, k = s & 7;
        int i = ig * 7 + k;
        float v = 0.0f;
        if (k < 7 && i < RES_) {
            float d = ((float)i * (1.0f / 49.0f)
                     - (float)(xlo + cxL) * (1.0f / 255.0f)) * S2;
            v = EX(-SQ(d));
        }
        gx[t] = v;
    }
    __syncthreads();

    // --- flattened scan of the 8 bucket segments + NN splat ---
    {
        int n0 = (int)cnt4[((0 << 5) + b) * 16 + part];
        int n1 = (int)cnt4[((1 << 5) + b) * 16 + part];
        int n2 = (int)cnt4[((2 << 5) + b) * 16 + part];
        int n3 = (int)cnt4[((3 << 5) + b) * 16 + part];
        int n4 = (int)cnt4[((4 << 5) + b) * 16 + part];
        int n5 = (int)cnt4[((5 << 5) + b) * 16 + part];
        int n6 = (int)cnt4[((6 << 5) + b) * 16 + part];
        int n7 = (int)cnt4[((7 << 5) + b) * 16 + part];
        int e0 = n0, e1 = e0 + n1, e2 = e1 + n2, e3 = e2 + n3;
        int e4 = e3 + n4, e5 = e4 + n5, e6 = e5 + n6, e7 = e6 + n7;
        const size_t seg = (size_t)(part << 10);
        for (int g = tid; g < e7; g += 1024) {
            int h = (g >= e0) + (g >= e1) + (g >= e2) + (g >= e3)
                  + (g >= e4) + (g >= e5) + (g >= e6);
            int start = h == 0 ? 0 : (h == 1 ? e0 : (h == 2 ? e1 : (h == 3 ? e2 :
                        (h == 4 ? e3 : (h == 5 ? e4 : (h == 6 ? e5 : e6))))));
            const uint4* sp = (const uint4*)(pkb + (((size_t)((h << 5) + b)) << 14) + seg);
            uint4 q = sp[g - start];
#pragma unroll
            for (int e = 0; e < 4; e++) {
                unsigned u = e == 0 ? q.x : (e == 1 ? q.y : (e == 2 ? q.z : q.w));
                int lx = (int)((u >> 24) & 255u) - xlo;
                int ly = (int)((u >> 16) & 255u) - ylo;
                if (((unsigned)lx < 64u) & ((unsigned)ly < 64u))
                    atomicAdd(tile + (lx << 5) + (ly >> 1),
                              (u & 0xffffu) << ((ly & 1) << 4));
            }
        }
    }
    __syncthreads();

    // --- stage1: tmp[i][cyL] = sum_cx gx[cx][i] * tile[cx][cyL] ---
    {
        int cyL = tid & 63;
        int ig  = (tid >> 6) & 7;           // wave-uniform
        int cxh = tid >> 9;                 // wave-uniform (0..1)
        float acc[7];
#pragma unroll
        for (int k = 0; k < 7; k++) acc[k] = 0.0f;
#pragma unroll 4
        for (int c = 0; c < 32; c++) {
            int cx = (cxh << 5) + c;
            unsigned wrd = tile[(cx << 5) + (cyL >> 1)];
            float hv = (float)((wrd >> ((cyL & 1) << 4)) & 0xffffu) * QINV;
            const float* g = gx + (cx << 6) + (ig << 3);
            float4 g0 = *(const float4*)(g);
            float4 g1 = *(const float4*)(g + 4);
            acc[0] += g0.x * hv;  acc[1] += g0.y * hv;
            acc[2] += g0.z * hv;  acc[3] += g0.w * hv;
            acc[4] += g1.x * hv;  acc[5] += g1.y * hv;
            acc[6] += g1.z * hv;                 // slot 7 = zero pad
        }
        float* tp = tmpP + (size_t)cxh * 3584 + (ig * 7) * 64 + cyL;
#pragma unroll
        for (int k = 0; k < 7; k++) tp[k * 64] = acc[k];
    }
    __syncthreads();
    for (int t = tid; t < 3584; t += 1024) tmpP[t] += tmpP[t + 3584];
    __syncthreads();

    // --- stage2: partial[i][j] = sum_cy tmp[i][cy] * gy[ylo+cy][j] ---
    {
        int j  = tid & 63;
        int iq = tid >> 6;                  // 0..15, use 0..13 (56 rows)
        if (iq < 14) {
            int jc = j < RES_ ? j : RES_ - 1;
            float xjS = (float)jc * (1.0f / 49.0f) * S2;
            float a0 = 0.f, a1 = 0.f, a2 = 0.f, a3 = 0.f;
            const float* tq = tmpP + (iq * 4) * 64;
#pragma unroll 4
            for (int c = 0; c < 64; c++) {
                float d = xjS - (float)(ylo + c) * (1.0f / 255.0f) * S2;
                float g = EX(-SQ(d));
                a0 += tq[c] * g;
                a1 += tq[64 + c] * g;
                a2 += tq[128 + c] * g;
                a3 += tq[192 + c] * g;
            }
            if (j < RES_) {
                float* dst = partial + (size_t)id * 2500;
                int i0 = iq * 4;
                if (i0 + 0 < RES_) dst[(i0 + 0) * RES_ + j] = a0;
                if (i0 + 1 < RES_) dst[(i0 + 1) * RES_ + j] = a1;
                if (i0 + 2 < RES_) dst[(i0 + 2) * RES_ + j] = a2;
                if (i0 + 3 < RES_) dst[(i0 + 3) * RES_ + j] = a3;
            }
        }
    }
    __syncthreads();                         // drains this block's stores

    // --- last block of batch b reduces the 16 partials (fixed order) ---
    if (tid == 0) {
        __threadfence();
        unsigned o = atomicAdd(&done[b], 1u);
        amLast = (o == 15u) ? 1u : 0u;
    }
    __syncthreads();
    if (amLast) {
        const float* p = partial + (size_t)b * 2500;
        for (int f = tid; f < 2500; f += 1024) {
            float s = 0.0f;
#pragma unroll
            for (int k = 0; k < 16; k++) s += p[(size_t)k * B_ * 2500 + f];
            out[(size_t)b * 2500 + f] = s;
        }
    }
}

// ---------------------------------------------------------------------------
extern "C" void kernel_launch(void* const* d_in, const int* in_sizes, int n_in,
                              void* d_out, int out_size, void* d_ws, size_t ws_size,
                              hipStream_t stream) {
    const float4* pts = (const float4*)d_in[0];
    unsigned* pkb  = (unsigned*)d_ws;                      // 256*16384 u32 = 16.8 MB
    unsigned* cnt4 = pkb + (size_t)256 * 16384;            // 4096 u32
    unsigned* done = cnt4 + 4096;                          // 32 u32
    float* partial = (float*)(done + 32);                  // 512*2500 f32 = 5.12 MB
    float* out = (float*)d_out;

    hipFuncSetAttribute((const void*)k_fused,
                        hipFuncAttributeMaxDynamicSharedMemorySize, 53248);

    k_bucket<<<256, 1024, 0, stream>>>(pts, pkb, cnt4, done);
    k_fused<<<512, 1024, 53248, stream>>>(pkb, cnt4, partial, done, out);
}

// Round 21
// 41.237 us; speedup vs baseline: 2.1971x; 2.1757x over previous
//
#include <hip/hip_runtime.h>
#include <math.h>

static constexpr int B_ = 32;
static constexpr int RES_ = 50;
static constexpr int CAP = 2048;            // per (hq,b,part) bucket capacity
#define NF (1.0f/(2.0f*0.05f*0.05f + 1e-8f))
#define QSCALE 2048.0f                      // u16 bin quantization
#define QINV   (1.0f / 2048.0f)
#define EX(x)  __builtin_amdgcn_exp2f(x)    // native v_exp_f32 (2^x)
#define SQ(x)  ((x)*(x))

// pack = ix<<24 | iy<<16 | v  (NN bins, quantized weight)
__device__ __forceinline__ unsigned packpt(float bx, float dy) {
    int ix = (int)(fminf(fmaxf(bx * 255.0f + 0.5f, 0.0f), 255.0f));
    int iy = (int)(fminf(fmaxf(dy * 255.0f + 0.5f, 0.0f), 255.0f));
    float pers = fminf(fabsf(dy - bx), 10.0f);
    unsigned v = (unsigned)(fminf(pers * pers * QSCALE, 65535.0f) + 0.5f);
    return ((unsigned)ix << 24) | ((unsigned)iy << 16) | v;
}

// ---------------------------------------------------------------------------
// K0: pack each point ONCE and bucket by region part = (iy>>6)*2 + (ix>>7).
//     Grid 256 = (hq:8, b:32), id%32==b. WAVE-AGGREGATED slot reservation:
//     per point, ballot-group lanes by part; one leader atomicAdd per
//     (wave x part) carrying popc; lane slot = base + popc(mask & lt).
//     Cuts same-address ds_add_rtn serialization 64x (8192 -> ~128/block).
//     Buckets padded to x4 with u=0 no-ops. Integer sums -> order-invariant.
//     pkb[(hq*32+b)][part:8][slot:CAP] u32; cnt4 = padded count / 4.
// ---------------------------------------------------------------------------
__global__ void __launch_bounds__(1024) k_bucket(const float4* __restrict__ pts,
                                                 unsigned* __restrict__ pkb,
                                                 unsigned* __restrict__ cnt4) {
    __shared__ unsigned lcnt[8];
    int id = blockIdx.x;
    int b = id & 31, hq = id >> 5;          // hq 0..7
    int tid = threadIdx.x;
    if (tid < 8) lcnt[tid] = 0u;
    __syncthreads();

    int lane = tid & 63;
    unsigned long long lt = (lane == 63) ? 0x7fffffffffffffffull
                                         : ((1ull << lane) - 1ull);
    const float4* src = pts + ((size_t)b << 15) + ((size_t)hq << 12);  // 4096 f4
    unsigned* mybase = pkb + ((size_t)id << 14);    // 8 * CAP u32 per block
    for (int t = tid; t < 4096; t += 1024) {
        float4 q = src[t];
#pragma unroll
        for (int h = 0; h < 2; h++) {
            float bx = h ? q.z : q.x;
            float dy = h ? q.w : q.y;
            unsigned u = packpt(bx, dy);
            int part = ((int)((u >> 22) & 3u) << 1) | (int)(u >> 31);
            unsigned slot = 0u;
#pragma unroll
            for (int k = 0; k < 8; k++) {
                unsigned long long m = __ballot(part == k);
                if (part == k) {
                    int leader = __ffsll((unsigned long long)m) - 1;
                    unsigned base = 0u;
                    if (lane == leader)
                        base = atomicAdd(&lcnt[k], (unsigned)__popcll(m));
                    base = (unsigned)__shfl((int)base, leader, 64);
                    slot = base + (unsigned)__popcll(m & lt);
                }
            }
            if (slot < (unsigned)CAP) mybase[(part << 11) + slot] = u;
        }
    }
    __syncthreads();
    if (tid < 8) {
        unsigned base = lcnt[tid]; if (base > (unsigned)CAP) base = CAP;
        unsigned padded = (base + 3u) & ~3u; if (padded > (unsigned)CAP) padded = CAP;
        for (unsigned k = base; k < padded; k++) mybase[((unsigned)tid << 11) + k] = 0u;
        cnt4[(id << 3) + tid] = padded >> 2;
    }
}

// ---------------------------------------------------------------------------
// K1: FUSED splat + both contractions (R18-proven structure, unchanged).
//     Grid 256 = (part:8, b:32), id%8==b%8. Block owns the 128x64 region
//     (xh=part&1, yo=part>>1); scans its 8 bucket segments (~8192 points,
//     uint4 loads, all lanes active) -> 1 packed ds_add_u32 per point.
//     Stage1: cx-contraction vs Gaussian-x slot table (slot ig*8+k -> row
//     i=ig*7+k, k<7, i<50). Stage2: cy-contraction, inline-exp Gaussian-y.
//     partial[part*32+b][50][50]. LDS: tile 16KB | gx 32KB | tmpP 28KB = 76KB.
// ---------------------------------------------------------------------------
__global__ void __launch_bounds__(1024, 1) k_fused(const unsigned* __restrict__ pkb,
                                                   const unsigned* __restrict__ cnt4,
                                                   float* __restrict__ partial) {
    extern __shared__ unsigned lds[];
    unsigned* tile = lds;                        // 4096 u32
    float* gx   = (float*)(lds + 4096);          // 8192 f32
    float* tmpP = (float*)(lds + 4096 + 8192);   // 7168 f32

    int id = blockIdx.x;
    int b    = id & 31;
    int part = id >> 5;                     // 0..7
    int xh = part & 1, yo = part >> 1;
    int tid = threadIdx.x;
    const float S2 = sqrtf(NF * 1.44269504f);   // const-folded

    // --- init: zero tile, build Gaussian-x slot table ---
    for (int t = tid; t < 4096; t += 1024) tile[t] = 0u;
    for (int t = tid; t < 8192; t += 1024) {
        int cxL = t >> 6, s = t & 63;
        int ig = s >> 3, k = s & 7;
        int i = ig * 7 + k;
        float v = 0.0f;
        if (k < 7 && i < RES_) {
            float d = ((float)i * (1.0f / 49.0f)
                     - (float)((xh << 7) + cxL) * (1.0f / 255.0f)) * S2;
            v = EX(-SQ(d));
        }
        gx[t] = v;
    }
    __syncthreads();

    // --- scan this region's 8 bucket segments + NN splat ---
    int xlo = xh << 7, ylo = yo << 6;
    for (int hq = 0; hq < 8; hq++) {
        int blk = (hq << 5) + b;
        int n4 = (int)cnt4[(blk << 3) + part];
        const uint4* src = (const uint4*)(pkb + ((size_t)blk << 14) + (part << 11));
        for (int t = tid; t < n4; t += 1024) {
            uint4 q = src[t];
#pragma unroll
            for (int e = 0; e < 4; e++) {
                unsigned u = e == 0 ? q.x : (e == 1 ? q.y : (e == 2 ? q.z : q.w));
                int lx = (int)(u >> 24) - xlo;
                int ly = (int)((u >> 16) & 255u) - ylo;
                if (((unsigned)lx < 128u) & ((unsigned)ly < 64u))
                    atomicAdd(tile + (lx << 5) + (ly >> 1),
                              (u & 0xffffu) << ((ly & 1) << 4));
            }
        }
    }
    __syncthreads();

    // --- stage1: tmp[i][cyL] = sum_cx gx[cx][i] * tile[cx][cyL] ---
    {
        int cyL = tid & 63;
        int ig  = (tid >> 6) & 7;           // wave-uniform
        int cxh = tid >> 9;                 // wave-uniform
        float acc[7];
#pragma unroll
        for (int k = 0; k < 7; k++) acc[k] = 0.0f;
#pragma unroll 4
        for (int c = 0; c < 64; c++) {
            int cx = (cxh << 6) + c;
            unsigned wrd = tile[(cx << 5) + (cyL >> 1)];
            float hv = (float)((wrd >> ((cyL & 1) << 4)) & 0xffffu) * QINV;
            const float* g = gx + (cx << 6) + (ig << 3);
            float4 g0 = *(const float4*)(g);
            float4 g1 = *(const float4*)(g + 4);
            acc[0] += g0.x * hv;  acc[1] += g0.y * hv;
            acc[2] += g0.z * hv;  acc[3] += g0.w * hv;
            acc[4] += g1.x * hv;  acc[5] += g1.y * hv;
            acc[6] += g1.z * hv;                 // slot 7 = zero pad
        }
        float* tp = tmpP + (size_t)cxh * 3584 + (ig * 7) * 64 + cyL;
#pragma unroll
        for (int k = 0; k < 7; k++) tp[k * 64] = acc[k];
    }
    __syncthreads();
    for (int t = tid; t < 3584; t += 1024) tmpP[t] += tmpP[t + 3584];
    __syncthreads();

    // --- stage2: out[i][j] = sum_cy tmp[i][cy] * gy[ylo+cy][j] ---
    {
        int j  = tid & 63;
        int iq = tid >> 6;                  // 0..15, use 0..13 (56 rows)
        if (iq < 14) {
            int jc = j < RES_ ? j : RES_ - 1;
            float xjS = (float)jc * (1.0f / 49.0f) * S2;
            float a0 = 0.f, a1 = 0.f, a2 = 0.f, a3 = 0.f;
            const float* tq = tmpP + (iq * 4) * 64;
#pragma unroll 4
            for (int c = 0; c < 64; c++) {
                float d = xjS - (float)(ylo + c) * (1.0f / 255.0f) * S2;
                float g = EX(-SQ(d));
                a0 += tq[c] * g;
                a1 += tq[64 + c] * g;
                a2 += tq[128 + c] * g;
                a3 += tq[192 + c] * g;
            }
            if (j < RES_) {
                float* dst = partial + (size_t)id * 2500;
                int i0 = iq * 4;
                if (i0 + 0 < RES_) dst[(i0 + 0) * RES_ + j] = a0;
                if (i0 + 1 < RES_) dst[(i0 + 1) * RES_ + j] = a1;
                if (i0 + 2 < RES_) dst[(i0 + 2) * RES_ + j] = a2;
                if (i0 + 3 < RES_) dst[(i0 + 3) * RES_ + j] = a3;
            }
        }
    }
}

// ---------------------------------------------------------------------------
// K2: out[b][f] = sum_{part<8} partial[part*32+b][f]
//     Grid 128 = (q:4, b:32), id%8==b%8 (partials XCD-local).
// ---------------------------------------------------------------------------
__global__ void __launch_bounds__(256) k_red(const float* __restrict__ partial,
                                             float* __restrict__ out) {
    int b  = blockIdx.x & 31;
    int qq = blockIdx.x >> 5;
    const float* p = partial + (size_t)b * 2500;
    int lo = qq * 625, hi = lo + 625;
    for (int f = lo + threadIdx.x; f < hi; f += 256) {
        float s = 0.0f;
#pragma unroll
        for (int k = 0; k < 8; k++) s += p[(size_t)k * 32 * 2500 + f];
        out[(size_t)b * 2500 + f] = s;
    }
}

// ---------------------------------------------------------------------------
extern "C" void kernel_launch(void* const* d_in, const int* in_sizes, int n_in,
                              void* d_out, int out_size, void* d_ws, size_t ws_size,
                              hipStream_t stream) {
    const float4* pts = (const float4*)d_in[0];
    unsigned* pkb  = (unsigned*)d_ws;                      // 256*16384 u32 = 16.8 MB
    unsigned* cnt4 = pkb + (size_t)256 * 16384;            // 2048 u32
    float* partial = (float*)(cnt4 + 2048);                // 256*2500 f32 = 2.56 MB
    float* out = (float*)d_out;

    hipFuncSetAttribute((const void*)k_fused,
                        hipFuncAttributeMaxDynamicSharedMemorySize, 77824);

    k_bucket<<<256, 1024, 0, stream>>>(pts, pkb, cnt4);
    k_fused<<<256, 1024, 77824, stream>>>(pkb, cnt4, partial);
    k_red<<<128, 256, 0, stream>>>(partial, out);
}

// Round 22
// 31.514 us; speedup vs baseline: 2.8750x; 1.3085x over previous
//
#include <hip/hip_runtime.h>
#include <math.h>

static constexpr int B_ = 32;
static constexpr int RES_ = 50;
static constexpr int CAP = 2048;            // per (hq,b,part) bucket capacity
#define NF (1.0f/(2.0f*0.05f*0.05f + 1e-8f))
#define QSCALE 2048.0f                      // u16 bin quantization
#define QINV   (1.0f / 2048.0f)
#define EX(x)  __builtin_amdgcn_exp2f(x)    // native v_exp_f32 (2^x)
#define SQ(x)  ((x)*(x))

// ---------------------------------------------------------------------------
// K0: pack each point ONCE (ix<<24 | iy<<16 | v) and BUCKET it by region
//     part = (iy>>6)*2 + (ix>>7), so the fused scan touches only its own
//     points with all 64 lanes active. Grid 256 = (hq:8, b:32), id%32==b;
//     each block handles 8192 points of batch b, reserving slots via native
//     LDS ds_add_rtn_u32 counters (plain per-lane atomics -- R21 proved
//     wave-aggregation costs more than the serialization it removes).
//     Buckets padded to x4 with v=0 no-ops.
//     pkb[(hq*32+b)][part:8][slot:CAP] u32; cnt4 = padded count / 4.
// ---------------------------------------------------------------------------
__device__ __forceinline__ unsigned packpt(float bx, float dy) {
    int ix = (int)(fminf(fmaxf(bx * 255.0f + 0.5f, 0.0f), 255.0f));
    int iy = (int)(fminf(fmaxf(dy * 255.0f + 0.5f, 0.0f), 255.0f));
    float pers = fminf(fabsf(dy - bx), 10.0f);
    unsigned v = (unsigned)(fminf(pers * pers * QSCALE, 65535.0f) + 0.5f);
    return ((unsigned)ix << 24) | ((unsigned)iy << 16) | v;
}

__global__ void __launch_bounds__(1024) k_bucket(const float4* __restrict__ pts,
                                                 unsigned* __restrict__ pkb,
                                                 unsigned* __restrict__ cnt4) {
    __shared__ unsigned lcnt[8];
    int id = blockIdx.x;
    int b = id & 31, hq = id >> 5;          // hq 0..7
    int tid = threadIdx.x;
    if (tid < 8) lcnt[tid] = 0u;
    __syncthreads();

    const float4* src = pts + ((size_t)b << 15) + ((size_t)hq << 12);  // 4096 f4
    unsigned* mybase = pkb + ((size_t)id << 14);    // 8 * CAP u32 per block
    for (int t = tid; t < 4096; t += 1024) {
        float4 q = src[t];
#pragma unroll
        for (int h = 0; h < 2; h++) {
            float bx = h ? q.z : q.x;
            float dy = h ? q.w : q.y;
            unsigned u = packpt(bx, dy);
            int part = ((int)((u >> 22) & 3u) << 1) | (int)(u >> 31);
            unsigned slot = atomicAdd(&lcnt[part], 1u);
            if (slot < (unsigned)CAP) mybase[(part << 11) + slot] = u;
        }
    }
    __syncthreads();
    if (tid < 8) {
        unsigned base = lcnt[tid]; if (base > (unsigned)CAP) base = CAP;
        unsigned padded = (base + 3u) & ~3u; if (padded > (unsigned)CAP) padded = CAP;
        for (unsigned k = base; k < padded; k++) mybase[((unsigned)tid << 11) + k] = 0u;
        cnt4[(id << 3) + tid] = padded >> 2;
    }
}

// ---------------------------------------------------------------------------
// K1: FUSED splat + both contractions (R18-proven structure, unchanged).
//     Grid 256 = (part:8, b:32), id%8==b%8. Block owns the 128x64 region
//     (xh=part&1, yo=part>>1); scans its 8 bucket segments (~8192 points,
//     uint4 loads, all lanes active) -> 1 packed ds_add_u32 per point.
//     Stage1: cx-contraction vs Gaussian-x slot table (slot ig*8+k -> row
//     i=ig*7+k, k<7, i<50). Stage2: cy-contraction, inline-exp Gaussian-y.
//     partial[part*32+b][50][50]. LDS: tile 16KB | gx 32KB | tmpP 28KB = 76KB.
// ---------------------------------------------------------------------------
__global__ void __launch_bounds__(1024, 1) k_fused(const unsigned* __restrict__ pkb,
                                                   const unsigned* __restrict__ cnt4,
                                                   float* __restrict__ partial) {
    extern __shared__ unsigned lds[];
    unsigned* tile = lds;                        // 4096 u32
    float* gx   = (float*)(lds + 4096);          // 8192 f32
    float* tmpP = (float*)(lds + 4096 + 8192);   // 7168 f32

    int id = blockIdx.x;
    int b    = id & 31;
    int part = id >> 5;                     // 0..7
    int xh = part & 1, yo = part >> 1;
    int tid = threadIdx.x;
    const float S2 = sqrtf(NF * 1.44269504f);   // const-folded

    // --- init: zero tile, build Gaussian-x slot table ---
    for (int t = tid; t < 4096; t += 1024) tile[t] = 0u;
    for (int t = tid; t < 8192; t += 1024) {
        int cxL = t >> 6, s = t & 63;
        int ig = s >> 3, k = s & 7;
        int i = ig * 7 + k;
        float v = 0.0f;
        if (k < 7 && i < RES_) {
            float d = ((float)i * (1.0f / 49.0f)
                     - (float)((xh << 7) + cxL) * (1.0f / 255.0f)) * S2;
            v = EX(-SQ(d));
        }
        gx[t] = v;
    }
    __syncthreads();

    // --- scan this region's 8 bucket segments + NN splat ---
    int xlo = xh << 7, ylo = yo << 6;
    for (int hq = 0; hq < 8; hq++) {
        int blk = (hq << 5) + b;
        int n4 = (int)cnt4[(blk << 3) + part];
        const uint4* src = (const uint4*)(pkb + ((size_t)blk << 14) + (part << 11));
        for (int t = tid; t < n4; t += 1024) {
            uint4 q = src[t];
#pragma unroll
            for (int e = 0; e < 4; e++) {
                unsigned u = e == 0 ? q.x : (e == 1 ? q.y : (e == 2 ? q.z : q.w));
                int lx = (int)(u >> 24) - xlo;
                int ly = (int)((u >> 16) & 255u) - ylo;
                if (((unsigned)lx < 128u) & ((unsigned)ly < 64u))
                    atomicAdd(tile + (lx << 5) + (ly >> 1),
                              (u & 0xffffu) << ((ly & 1) << 4));
            }
        }
    }
    __syncthreads();

    // --- stage1: tmp[i][cyL] = sum_cx gx[cx][i] * tile[cx][cyL] ---
    {
        int cyL = tid & 63;
        int ig  = (tid >> 6) & 7;           // wave-uniform
        int cxh = tid >> 9;                 // wave-uniform
        float acc[7];
#pragma unroll
        for (int k = 0; k < 7; k++) acc[k] = 0.0f;
#pragma unroll 4
        for (int c = 0; c < 64; c++) {
            int cx = (cxh << 6) + c;
            unsigned wrd = tile[(cx << 5) + (cyL >> 1)];
            float hv = (float)((wrd >> ((cyL & 1) << 4)) & 0xffffu) * QINV;
            const float* g = gx + (cx << 6) + (ig << 3);
            float4 g0 = *(const float4*)(g);
            float4 g1 = *(const float4*)(g + 4);
            acc[0] += g0.x * hv;  acc[1] += g0.y * hv;
            acc[2] += g0.z * hv;  acc[3] += g0.w * hv;
            acc[4] += g1.x * hv;  acc[5] += g1.y * hv;
            acc[6] += g1.z * hv;                 // slot 7 = zero pad
        }
        float* tp = tmpP + (size_t)cxh * 3584 + (ig * 7) * 64 + cyL;
#pragma unroll
        for (int k = 0; k < 7; k++) tp[k * 64] = acc[k];
    }
    __syncthreads();
    for (int t = tid; t < 3584; t += 1024) tmpP[t] += tmpP[t + 3584];
    __syncthreads();

    // --- stage2: out[i][j] = sum_cy tmp[i][cy] * gy[ylo+cy][j] ---
    {
        int j  = tid & 63;
        int iq = tid >> 6;                  // 0..15, use 0..13 (56 rows)
        if (iq < 14) {
            int jc = j < RES_ ? j : RES_ - 1;
            float xjS = (float)jc * (1.0f / 49.0f) * S2;
            float a0 = 0.f, a1 = 0.f, a2 = 0.f, a3 = 0.f;
            const float* tq = tmpP + (iq * 4) * 64;
#pragma unroll 4
            for (int c = 0; c < 64; c++) {
                float d = xjS - (float)(ylo + c) * (1.0f / 255.0f) * S2;
                float g = EX(-SQ(d));
                a0 += tq[c] * g;
                a1 += tq[64 + c] * g;
                a2 += tq[128 + c] * g;
                a3 += tq[192 + c] * g;
            }
            if (j < RES_) {
                float* dst = partial + (size_t)id * 2500;
                int i0 = iq * 4;
                if (i0 + 0 < RES_) dst[(i0 + 0) * RES_ + j] = a0;
                if (i0 + 1 < RES_) dst[(i0 + 1) * RES_ + j] = a1;
                if (i0 + 2 < RES_) dst[(i0 + 2) * RES_ + j] = a2;
                if (i0 + 3 < RES_) dst[(i0 + 3) * RES_ + j] = a3;
            }
        }
    }
}

// ---------------------------------------------------------------------------
// K2: out[b][f] = sum_{part<8} partial[part*32+b][f]
//     Grid 128 = (q:4, b:32), id%8==b%8 (partials XCD-local).
// ---------------------------------------------------------------------------
__global__ void __launch_bounds__(256) k_red(const float* __restrict__ partial,
                                             float* __restrict__ out) {
    int b  = blockIdx.x & 31;
    int qq = blockIdx.x >> 5;
    const float* p = partial + (size_t)b * 2500;
    int lo = qq * 625, hi = lo + 625;
    for (int f = lo + threadIdx.x; f < hi; f += 256) {
        float s = 0.0f;
#pragma unroll
        for (int k = 0; k < 8; k++) s += p[(size_t)k * 32 * 2500 + f];
        out[(size_t)b * 2500 + f] = s;
    }
}

// ---------------------------------------------------------------------------
extern "C" void kernel_launch(void* const* d_in, const int* in_sizes, int n_in,
                              void* d_out, int out_size, void* d_ws, size_t ws_size,
                              hipStream_t stream) {
    const float4* pts = (const float4*)d_in[0];
    unsigned* pkb  = (unsigned*)d_ws;                      // 256*16384 u32 = 16.8 MB
    unsigned* cnt4 = pkb + (size_t)256 * 16384;            // 2048 u32
    float* partial = (float*)(cnt4 + 2048);                // 256*2500 f32 = 2.56 MB
    float* out = (float*)d_out;

    hipFuncSetAttribute((const void*)k_fused,
                        hipFuncAttributeMaxDynamicSharedMemorySize, 77824);

    k_bucket<<<256, 1024, 0, stream>>>(pts, pkb, cnt4);
    k_fused<<<256, 1024, 77824, stream>>>(pkb, cnt4, partial);
    k_red<<<128, 256, 0, stream>>>(partial, out);
}